// Round 1
// baseline (6012.468 us; speedup 1.0000x reference)
//
#include <hip/hip_runtime.h>
#include <hip/hip_bf16.h>
#include <cstddef>

// ---------------------------------------------------------------------------
// EncoderModule: 5x causal conv1d (K=7) + ELU, then 2x VQ argmin (1024 codes, D=64)
// B=64, L=48000, strides 2,2,2,3,1; channels 1->16->32->64->64->128
// Output: int32 indices, shape (2, 64, 2000)
// ---------------------------------------------------------------------------

#define K_SIZE 7

// Generic causal-conv + ELU. Layout: x (B, CIN, Lin), w (Cout, CIN, 7), y (B, Cout, Lout).
// One thread per output element; gid = b*Cout*Lout + co*Lout + t (t fastest -> coalesced stores).
template<int CIN, int STRIDE>
__global__ __launch_bounds__(256) void conv_elu_kernel(
    const float* __restrict__ x, const float* __restrict__ w,
    const float* __restrict__ bias, float* __restrict__ y,
    int B, int Lin, int Lout, int Cout)
{
    int gid = blockIdx.x * blockDim.x + threadIdx.x;
    int total = B * Cout * Lout;
    if (gid >= total) return;
    int t  = gid % Lout;
    int co = (gid / Lout) % Cout;
    int b  = gid / (Lout * Cout);

    const float* wrow = w + (size_t)co * CIN * K_SIZE;
    const float* xb   = x + (size_t)b * CIN * Lin;

    float acc = bias[co];
    int base = t * STRIDE - (K_SIZE - 1);   // leftmost tap in input coords

    if (base >= 0) {
        for (int ci = 0; ci < CIN; ++ci) {
            const float* xr = xb + (size_t)ci * Lin + base;
            #pragma unroll
            for (int k = 0; k < K_SIZE; ++k)
                acc = fmaf(wrow[ci * K_SIZE + k], xr[k], acc);
        }
    } else {
        // left edge: taps with base+k < 0 read implicit zero padding
        for (int ci = 0; ci < CIN; ++ci) {
            const float* xr = xb + (size_t)ci * Lin;
            #pragma unroll
            for (int k = 0; k < K_SIZE; ++k) {
                int ix = base + k;
                if (ix >= 0)
                    acc = fmaf(wrow[ci * K_SIZE + k], xr[ix], acc);
            }
        }
    }
    // ELU (alpha=1): x>0 ? x : expm1(x)
    y[gid] = acc > 0.0f ? acc : expm1f(acc);
}

// VQ argmin: block handles one (b, 16-wide t tile, codebook).
// z: (B, 128, T); codebook cb uses channels [cb*64, cb*64+64).
// codebooks: (2, 1024, 64). Each thread owns 4 codes (tid, tid+256, tid+512, tid+768).
#define TT 16
__global__ __launch_bounds__(256) void vq_kernel(
    const float* __restrict__ z, const float* __restrict__ cbs,
    int* __restrict__ out, int B, int T)
{
    __shared__ float zs[64][TT];
    __shared__ float rv[256];
    __shared__ int   ri[256];

    int bid   = blockIdx.x;
    int ntile = T / TT;
    int cb    = bid & 1;
    int tile  = (bid >> 1) % ntile;
    int b     = bid / (2 * ntile);
    int t0    = tile * TT;
    int tid   = threadIdx.x;

    // stage z tile: zs[d][t]
    for (int i = tid; i < 64 * TT; i += 256) {
        int d = i / TT, t = i % TT;
        zs[d][t] = z[((size_t)(b * 128 + cb * 64 + d)) * T + t0 + t];
    }
    __syncthreads();

    const float* cbase = cbs + (size_t)cb * 1024 * 64;

    float acc[4][TT];
    #pragma unroll
    for (int j = 0; j < 4; ++j)
        #pragma unroll
        for (int t = 0; t < TT; ++t) acc[j][t] = 0.0f;

    for (int d4 = 0; d4 < 16; ++d4) {
        float4 cv[4];
        #pragma unroll
        for (int j = 0; j < 4; ++j) {
            int code = j * 256 + tid;
            cv[j] = *(const float4*)(cbase + (size_t)code * 64 + d4 * 4);
        }
        #pragma unroll
        for (int dd = 0; dd < 4; ++dd) {
            float zv[TT];
            #pragma unroll
            for (int t = 0; t < TT; ++t) zv[t] = zs[d4 * 4 + dd][t];
            #pragma unroll
            for (int j = 0; j < 4; ++j) {
                float c = (dd == 0) ? cv[j].x : (dd == 1) ? cv[j].y : (dd == 2) ? cv[j].z : cv[j].w;
                #pragma unroll
                for (int t = 0; t < TT; ++t) {
                    float diff = zv[t] - c;
                    acc[j][t] = fmaf(diff, diff, acc[j][t]);
                }
            }
        }
    }

    // local argmin over this thread's 4 codes (ascending code index -> strict < keeps first)
    float mv[TT]; int mi[TT];
    #pragma unroll
    for (int t = 0; t < TT; ++t) {
        mv[t] = acc[0][t]; mi[t] = tid;
        #pragma unroll
        for (int j = 1; j < 4; ++j) {
            if (acc[j][t] < mv[t]) { mv[t] = acc[j][t]; mi[t] = j * 256 + tid; }
        }
    }

    // block argmin per t (first-occurrence tie-break: smaller code index wins on equal value)
    for (int t = 0; t < TT; ++t) {
        rv[tid] = mv[t]; ri[tid] = mi[t];
        __syncthreads();
        for (int s = 128; s > 0; s >>= 1) {
            if (tid < s) {
                float ov = rv[tid + s]; int oi = ri[tid + s];
                if (ov < rv[tid] || (ov == rv[tid] && oi < ri[tid])) { rv[tid] = ov; ri[tid] = oi; }
            }
            __syncthreads();
        }
        if (tid == 0) out[((size_t)cb * B + b) * T + t0 + t] = ri[0];
        __syncthreads();
    }
}

extern "C" void kernel_launch(void* const* d_in, const int* in_sizes, int n_in,
                              void* d_out, int out_size, void* d_ws, size_t ws_size,
                              hipStream_t stream)
{
    const float* x   = (const float*)d_in[0];
    const float* w0  = (const float*)d_in[1];
    const float* b0  = (const float*)d_in[2];
    const float* w1  = (const float*)d_in[3];
    const float* b1  = (const float*)d_in[4];
    const float* w2  = (const float*)d_in[5];
    const float* b2  = (const float*)d_in[6];
    const float* w3  = (const float*)d_in[7];
    const float* b3  = (const float*)d_in[8];
    const float* wq  = (const float*)d_in[9];
    const float* bq  = (const float*)d_in[10];
    const float* cbs = (const float*)d_in[11];
    int* out = (int*)d_out;

    constexpr int B = 64;
    // buffer sizes (floats): h1 = 64*16*24000 = h2 = 64*32*12000 = h3 = 64*64*6000 = 24,576,000
    constexpr size_t BUF = 24576000;
    float* bufA = (float*)d_ws;
    float* bufB = bufA + BUF;

    auto nblocks = [](long total) { return (int)((total + 255) / 256); };

    // conv0: (B,1,48000) -> (B,16,24000)
    conv_elu_kernel<1, 2><<<nblocks((long)B * 16 * 24000), 256, 0, stream>>>(
        x, w0, b0, bufA, B, 48000, 24000, 16);
    // conv1: (B,16,24000) -> (B,32,12000)
    conv_elu_kernel<16, 2><<<nblocks((long)B * 32 * 12000), 256, 0, stream>>>(
        bufA, w1, b1, bufB, B, 24000, 12000, 32);
    // conv2: (B,32,12000) -> (B,64,6000)
    conv_elu_kernel<32, 2><<<nblocks((long)B * 64 * 6000), 256, 0, stream>>>(
        bufB, w2, b2, bufA, B, 12000, 6000, 64);
    // conv3: (B,64,6000) -> (B,64,2000)
    conv_elu_kernel<64, 3><<<nblocks((long)B * 64 * 2000), 256, 0, stream>>>(
        bufA, w3, b3, bufB, B, 6000, 2000, 64);
    // conv4 (pre-quant): (B,64,2000) -> (B,128,2000)
    conv_elu_kernel<64, 1><<<nblocks((long)B * 128 * 2000), 256, 0, stream>>>(
        bufB, wq, bq, bufA, B, 2000, 2000, 128);

    // VQ: (B,128,2000) -> indices (2,B,2000)
    int T = 2000;
    int nblk = B * (T / TT) * 2;   // 64 * 125 * 2 = 16000
    vq_kernel<<<nblk, 256, 0, stream>>>(bufA, cbs, out, B, T);
}

// Round 2
// 1437.652 us; speedup vs baseline: 4.1821x; 4.1821x over previous
//
#include <hip/hip_runtime.h>
#include <hip/hip_bf16.h>
#include <cstddef>

// ---------------------------------------------------------------------------
// EncoderModule: 5x causal conv1d (K=7) + ELU, then 2x VQ argmin (1024 codes, D=64)
// B=64, L=48000, strides 2,2,2,3,1; channels 1->16->32->64->64->128
// Output: int32 indices, shape (2, 64, 2000)
//
// Conv design: block = 4 waves x 64 lanes. lane = output t (64 consecutive t per
// block), each wave owns CO_T consecutive output channels (wave-uniform index via
// readfirstlane -> weight/bias loads become scalar s_loads through the constant
// cache). Input tile staged in LDS once per block. Inner loop per ci:
// 7 LDS reads + CO_T*7 FMAs -> VALU-bound.
// ---------------------------------------------------------------------------

template<int CIN, int S, int CO_T>
__global__ __launch_bounds__(256) void conv_wave_kernel(
    const float* __restrict__ x, const float* __restrict__ w,
    const float* __restrict__ bias, float* __restrict__ y,
    int B, int Lin, int Lout, int Cout)
{
    constexpr int XLEN = 63 * S + 7;          // input span for 64 outputs
    __shared__ float xs[CIN][XLEN];

    int tb  = blockIdx.x;                      // t-block (64 outputs)
    int cbk = blockIdx.y;                      // co-block (4*CO_T channels)
    int b   = blockIdx.z;
    int t0  = tb * 64;
    int tid  = threadIdx.x;
    int lane = tid & 63;
    int wv   = __builtin_amdgcn_readfirstlane(tid >> 6);   // wave id, uniform

    // stage input tile (zero-filled causal left pad, bound-checked right)
    const float* xb = x + (size_t)b * CIN * Lin;
    int g0 = t0 * S - 6;
    for (int i = tid; i < CIN * XLEN; i += 256) {
        int ci = i / XLEN, xo = i % XLEN;
        int gx = g0 + xo;
        xs[ci][xo] = (gx >= 0 && gx < Lin) ? xb[(size_t)ci * Lin + gx] : 0.0f;
    }
    __syncthreads();

    int co0 = cbk * (4 * CO_T) + wv * CO_T;    // uniform per wave
    const float* wbase = w + (size_t)co0 * CIN * 7;

    float acc[CO_T];
    #pragma unroll
    for (int c = 0; c < CO_T; ++c) acc[c] = 0.0f;

    for (int ci = 0; ci < CIN; ++ci) {
        float xw[7];
        #pragma unroll
        for (int k = 0; k < 7; ++k) xw[k] = xs[ci][lane * S + k];
        #pragma unroll
        for (int c = 0; c < CO_T; ++c) {
            const float* wp = wbase + (size_t)c * CIN * 7 + ci * 7;  // uniform -> s_load
            #pragma unroll
            for (int k = 0; k < 7; ++k)
                acc[c] = fmaf(wp[k], xw[k], acc[c]);
        }
    }

    int t = t0 + lane;
    if (t < Lout) {
        #pragma unroll
        for (int c = 0; c < CO_T; ++c) {
            float v = acc[c] + bias[co0 + c];
            y[((size_t)b * Cout + co0 + c) * Lout + t] = v > 0.0f ? v : expm1f(v);
        }
    }
}

// ---------------------------------------------------------------------------
// VQ: score(t,c) = ||c||^2 - 2 * dot(z_t, c)  (same expansion as the reference;
// ||z||^2 is constant in c). z-row held in 64 VGPRs for the whole code loop;
// codebook rows are loop-uniform -> scalar s_loads. Strict < keeps the first
// occurrence on ties, matching jnp.argmin.
// ---------------------------------------------------------------------------

__global__ __launch_bounds__(256) void cc_kernel(
    const float* __restrict__ cbs, float* __restrict__ cc)
{
    int c = blockIdx.x * 256 + threadIdx.x;    // 2048 codes total
    if (c >= 2048) return;
    const float4* p = (const float4*)(cbs + (size_t)c * 64);
    float s = 0.0f;
    #pragma unroll
    for (int i = 0; i < 16; ++i) {
        float4 v = p[i];
        s += v.x * v.x + v.y * v.y + v.z * v.z + v.w * v.w;
    }
    cc[c] = s;
}

__global__ __launch_bounds__(256) void vq_dot_kernel(
    const float* __restrict__ z, const float* __restrict__ cbs,
    const float* __restrict__ cc, int* __restrict__ out, int B, int T)
{
    int tb = blockIdx.x, cb = blockIdx.y, b = blockIdx.z;
    int tid = threadIdx.x;
    int t  = tb * 256 + tid;
    int tc = t < T ? t : T - 1;                // clamp for load, mask at store

    const float* zb = z + ((size_t)b * 128 + (size_t)cb * 64) * T;
    float zr[64];
    #pragma unroll
    for (int d = 0; d < 64; ++d) zr[d] = zb[(size_t)d * T + tc];

    const float* cbase = cbs + (size_t)cb * 1024 * 64;
    const float* ccb   = cc + cb * 1024;

    float bestv = 3.4e38f;
    int   besti = 0;
    for (int c = 0; c < 1024; ++c) {
        const float* cp = cbase + (size_t)c * 64;   // uniform -> s_load
        float d0 = 0.f, d1 = 0.f, d2 = 0.f, d3 = 0.f;
        #pragma unroll
        for (int d = 0; d < 64; d += 4) {
            d0 = fmaf(zr[d + 0], cp[d + 0], d0);
            d1 = fmaf(zr[d + 1], cp[d + 1], d1);
            d2 = fmaf(zr[d + 2], cp[d + 2], d2);
            d3 = fmaf(zr[d + 3], cp[d + 3], d3);
        }
        float dot = (d0 + d1) + (d2 + d3);
        float s = fmaf(-2.0f, dot, ccb[c]);
        if (s < bestv) { bestv = s; besti = c; }
    }
    if (t < T) out[((size_t)cb * B + b) * T + t] = besti;
}

extern "C" void kernel_launch(void* const* d_in, const int* in_sizes, int n_in,
                              void* d_out, int out_size, void* d_ws, size_t ws_size,
                              hipStream_t stream)
{
    const float* x   = (const float*)d_in[0];
    const float* w0  = (const float*)d_in[1];
    const float* b0  = (const float*)d_in[2];
    const float* w1  = (const float*)d_in[3];
    const float* b1  = (const float*)d_in[4];
    const float* w2  = (const float*)d_in[5];
    const float* b2  = (const float*)d_in[6];
    const float* w3  = (const float*)d_in[7];
    const float* b3  = (const float*)d_in[8];
    const float* wq  = (const float*)d_in[9];
    const float* bq  = (const float*)d_in[10];
    const float* cbs = (const float*)d_in[11];
    int* out = (int*)d_out;

    constexpr int B = 64;
    constexpr size_t BUF = 24576000;   // max intermediate (floats)
    float* bufA = (float*)d_ws;
    float* bufB = bufA + BUF;

    // conv0: (B,1,48000) -> (B,16,24000)   Cout=16 = 4 waves * CO_T=4
    conv_wave_kernel<1, 2, 4><<<dim3(375, 1, B), 256, 0, stream>>>(
        x, w0, b0, bufA, B, 48000, 24000, 16);
    // conv1: (B,16,24000) -> (B,32,12000)  Cout=32 = 4*8
    conv_wave_kernel<16, 2, 8><<<dim3(188, 1, B), 256, 0, stream>>>(
        bufA, w1, b1, bufB, B, 24000, 12000, 32);
    // conv2: (B,32,12000) -> (B,64,6000)   2 co-blocks of 32
    conv_wave_kernel<32, 2, 8><<<dim3(94, 2, B), 256, 0, stream>>>(
        bufB, w2, b2, bufA, B, 12000, 6000, 64);
    // conv3: (B,64,6000) -> (B,64,2000)    stride 3
    conv_wave_kernel<64, 3, 8><<<dim3(32, 2, B), 256, 0, stream>>>(
        bufA, w3, b3, bufB, B, 6000, 2000, 64);
    // conv4: (B,64,2000) -> (B,128,2000)   stride 1, 4 co-blocks
    conv_wave_kernel<64, 1, 8><<<dim3(32, 4, B), 256, 0, stream>>>(
        bufB, wq, bq, bufA, B, 2000, 2000, 128);

    // ||c||^2 for both codebooks -> bufB (dead after conv4)
    float* cc = bufB;
    cc_kernel<<<8, 256, 0, stream>>>(cbs, cc);

    // VQ argmin -> out (2, B, 2000)
    vq_dot_kernel<<<dim3(8, 2, B), 256, 0, stream>>>(bufA, cbs, cc, out, B, 2000);
}

// Round 3
// 1434.077 us; speedup vs baseline: 4.1926x; 1.0025x over previous
//
#include <hip/hip_runtime.h>
#include <hip/hip_bf16.h>
#include <cstddef>

// ---------------------------------------------------------------------------
// EncoderModule: 5x causal conv1d (K=7) + ELU, then 2x VQ argmin (1024 codes, D=64)
// B=64, L=48000, strides 2,2,2,3,1; channels 1->16->32->64->64->128
// Output: int32 indices, shape (2, 64, 2000)
// ---------------------------------------------------------------------------

template<int CIN, int S, int CO_T>
__global__ __launch_bounds__(256) void conv_wave_kernel(
    const float* __restrict__ x, const float* __restrict__ w,
    const float* __restrict__ bias, float* __restrict__ y,
    int B, int Lin, int Lout, int Cout)
{
    constexpr int XLEN = 63 * S + 7;          // input span for 64 outputs
    __shared__ float xs[CIN][XLEN];

    int tb  = blockIdx.x;                      // t-block (64 outputs)
    int cbk = blockIdx.y;                      // co-block (4*CO_T channels)
    int b   = blockIdx.z;
    int t0  = tb * 64;
    int tid  = threadIdx.x;
    int lane = tid & 63;
    int wv   = __builtin_amdgcn_readfirstlane(tid >> 6);   // wave id, uniform

    // stage input tile (zero-filled causal left pad, bound-checked right)
    const float* xb = x + (size_t)b * CIN * Lin;
    int g0 = t0 * S - 6;
    for (int i = tid; i < CIN * XLEN; i += 256) {
        int ci = i / XLEN, xo = i % XLEN;
        int gx = g0 + xo;
        xs[ci][xo] = (gx >= 0 && gx < Lin) ? xb[(size_t)ci * Lin + gx] : 0.0f;
    }
    __syncthreads();

    int co0 = cbk * (4 * CO_T) + wv * CO_T;    // uniform per wave
    const float* wbase = w + (size_t)co0 * CIN * 7;

    float acc[CO_T];
    #pragma unroll
    for (int c = 0; c < CO_T; ++c) acc[c] = 0.0f;

    for (int ci = 0; ci < CIN; ++ci) {
        float xw[7];
        #pragma unroll
        for (int k = 0; k < 7; ++k) xw[k] = xs[ci][lane * S + k];
        #pragma unroll
        for (int c = 0; c < CO_T; ++c) {
            const float* wp = wbase + (size_t)c * CIN * 7 + ci * 7;  // uniform -> s_load
            #pragma unroll
            for (int k = 0; k < 7; ++k)
                acc[c] = fmaf(wp[k], xw[k], acc[c]);
        }
    }

    int t = t0 + lane;
    if (t < Lout) {
        #pragma unroll
        for (int c = 0; c < CO_T; ++c) {
            float v = acc[c] + bias[co0 + c];
            y[((size_t)b * Cout + co0 + c) * Lout + t] = v > 0.0f ? v : expm1f(v);
        }
    }
}

// ---------------------------------------------------------------------------
// VQ: score(t,c) = ||c||^2 - 2 * dot(z_t, c). z-row pinned in 64 VGPRs for the
// whole 1024-code loop (asm pin prevents the allocator from rematerializing the
// strided global loads inside the loop). Codebook rows are loop-uniform ->
// scalar s_loads on the SMEM pipe. Strict < keeps first occurrence on ties.
// ---------------------------------------------------------------------------

__global__ __launch_bounds__(256) void cc_kernel(
    const float* __restrict__ cbs, float* __restrict__ cc)
{
    int c = blockIdx.x * 256 + threadIdx.x;    // 2048 codes total
    if (c >= 2048) return;
    const float4* p = (const float4*)(cbs + (size_t)c * 64);
    float s = 0.0f;
    #pragma unroll
    for (int i = 0; i < 16; ++i) {
        float4 v = p[i];
        s += v.x * v.x + v.y * v.y + v.z * v.z + v.w * v.w;
    }
    cc[c] = s;
}

__global__ __launch_bounds__(256, 1) void vq_dot_kernel(
    const float* __restrict__ z, const float* __restrict__ cbs,
    const float* __restrict__ cc, int* __restrict__ out, int B, int T)
{
    int tb = blockIdx.x, cb = blockIdx.y, b = blockIdx.z;
    int tid = threadIdx.x;
    int t  = tb * 256 + tid;
    int tc = t < T ? t : T - 1;                // clamp for load, mask at store

    const float* zb = z + ((size_t)b * 128 + (size_t)cb * 64) * T;
    float zr[64];
    #pragma unroll
    for (int d = 0; d < 64; ++d) zr[d] = zb[(size_t)d * T + tc];
    // Pin the z-row into VGPRs: value flows through opaque asm, so the register
    // allocator cannot rematerialize the loads inside the code loop.
    #pragma unroll
    for (int d = 0; d < 64; ++d) asm volatile("" : "+v"(zr[d]));

    const float* cbase = cbs + (size_t)cb * 1024 * 64;
    const float* ccb   = cc + cb * 1024;

    float bestv = 3.4e38f;
    int   besti = 0;
    for (int c = 0; c < 1024; ++c) {
        const float* cp = cbase + (size_t)c * 64;   // uniform -> s_load
        float d0 = 0.f, d1 = 0.f, d2 = 0.f, d3 = 0.f;
        #pragma unroll
        for (int d = 0; d < 64; d += 4) {
            d0 = fmaf(zr[d + 0], cp[d + 0], d0);
            d1 = fmaf(zr[d + 1], cp[d + 1], d1);
            d2 = fmaf(zr[d + 2], cp[d + 2], d2);
            d3 = fmaf(zr[d + 3], cp[d + 3], d3);
        }
        float dot = (d0 + d1) + (d2 + d3);
        float s = fmaf(-2.0f, dot, ccb[c]);
        if (s < bestv) { bestv = s; besti = c; }
    }
    if (t < T) out[((size_t)cb * B + b) * T + t] = besti;
}

extern "C" void kernel_launch(void* const* d_in, const int* in_sizes, int n_in,
                              void* d_out, int out_size, void* d_ws, size_t ws_size,
                              hipStream_t stream)
{
    const float* x   = (const float*)d_in[0];
    const float* w0  = (const float*)d_in[1];
    const float* b0  = (const float*)d_in[2];
    const float* w1  = (const float*)d_in[3];
    const float* b1  = (const float*)d_in[4];
    const float* w2  = (const float*)d_in[5];
    const float* b2  = (const float*)d_in[6];
    const float* w3  = (const float*)d_in[7];
    const float* b3  = (const float*)d_in[8];
    const float* wq  = (const float*)d_in[9];
    const float* bq  = (const float*)d_in[10];
    const float* cbs = (const float*)d_in[11];
    int* out = (int*)d_out;

    constexpr int B = 64;
    constexpr size_t BUF = 24576000;   // max intermediate (floats)
    float* bufA = (float*)d_ws;
    float* bufB = bufA + BUF;

    // conv0: (B,1,48000) -> (B,16,24000)   Cout=16 = 4 waves * CO_T=4
    conv_wave_kernel<1, 2, 4><<<dim3(375, 1, B), 256, 0, stream>>>(
        x, w0, b0, bufA, B, 48000, 24000, 16);
    // conv1: (B,16,24000) -> (B,32,12000)  Cout=32 = 4*8
    conv_wave_kernel<16, 2, 8><<<dim3(188, 1, B), 256, 0, stream>>>(
        bufA, w1, b1, bufB, B, 24000, 12000, 32);
    // conv2: (B,32,12000) -> (B,64,6000)   2 co-blocks of 32
    conv_wave_kernel<32, 2, 8><<<dim3(94, 2, B), 256, 0, stream>>>(
        bufB, w2, b2, bufA, B, 12000, 6000, 64);
    // conv3: (B,64,6000) -> (B,64,2000)    stride 3
    conv_wave_kernel<64, 3, 8><<<dim3(32, 2, B), 256, 0, stream>>>(
        bufA, w3, b3, bufB, B, 6000, 2000, 64);
    // conv4: (B,64,2000) -> (B,128,2000)   stride 1, 4 co-blocks
    conv_wave_kernel<64, 1, 8><<<dim3(32, 4, B), 256, 0, stream>>>(
        bufB, wq, bq, bufA, B, 2000, 2000, 128);

    // ||c||^2 for both codebooks -> bufB (dead after conv4)
    float* cc = bufB;
    cc_kernel<<<8, 256, 0, stream>>>(cbs, cc);

    // VQ argmin -> out (2, B, 2000)
    vq_dot_kernel<<<dim3(8, 2, B), 256, 0, stream>>>(bufA, cbs, cc, out, B, 2000);
}